// Round 11
// baseline (588.234 us; speedup 1.0000x reference)
//
#include <hip/hip_runtime.h>
#include <hip/hip_fp16.h>
#include <math.h>

#define NN 50000
#define EE 800000
#define TOT_EDGES (EE + NN)   // with self loops
#define FD 3
#define C 64
#define FC 512
#define NODES_PER_GRAPH 5000
#define NUM_GRAPHS 10
#define POOL_CHUNKS 40        // 5000 / 125
#define POOL_NODES_PER_CHUNK 125
#define NEG_SLOPE 0.2f

#define SCAN_BLK 1024
#define SCAN_GRID ((NN + SCAN_BLK - 1) / SCAN_BLK)   // 49

#define AGG_BLOCKS 2048       // grid-stride aggregate: 8192 waves, ~6 nodes/wave

// XCD-range-partitioned CSR build (see R5): keeps each XCD's scatter footprint
// L2-resident so line writes coalesce in L2 instead of 64B-per-edge HBM writebacks.
#define NPART 8
#define PART_NODES ((NN + NPART - 1) / NPART)        // 6250
#define CSR_EPT 8
#define CSR_CHUNK (256 * CSR_EPT)                    // 2048 edges / block
#define CSR_CHUNKS ((TOT_EDGES + CSR_CHUNK - 1) / CSR_CHUNK)

// prep-buffer offsets (floats): W@a_s / W@a_d per layer
#define OFF_W1AS 0
#define OFF_W1AD 4
#define OFF_WAS2 8
#define OFF_WAD2 72
#define OFF_WAS3 136
#define OFF_WAD3 200
#define OFF_WAS4 264
#define OFF_WAD4 328
#define WA_FLOATS 392

// ---------------- CSR build ----------------

__global__ void k_init_counts(int* counts) {
    int i = blockIdx.x * blockDim.x + threadIdx.x;
    if (i < NN) counts[i] = 0;   // self loops folded into partitioned count
}

__global__ void k_count_part(const int* __restrict__ dst, int* __restrict__ counts) {
    int part = blockIdx.x & (NPART - 1);
    int chunk = blockIdx.x >> 3;
    int lo = part * PART_NODES, hi = lo + PART_NODES;
    int base = chunk * CSR_CHUNK + threadIdx.x;
#pragma unroll
    for (int e = 0; e < CSR_EPT; ++e) {
        int i = base + e * 256;
        if (i < TOT_EDGES) {
            int d = (i < EE) ? dst[i] : (i - EE);
            if (d >= lo && d < hi) atomicAdd(&counts[d], 1);
        }
    }
}

__global__ void k_scan1(const int* __restrict__ counts, int* __restrict__ offsets,
                        int* __restrict__ blocksums) {
    int tid = threadIdx.x, blk = blockIdx.x;
    int i = blk * SCAN_BLK + tid;
    int v = (i < NN) ? counts[i] : 0;
    __shared__ int buf[SCAN_BLK];
    buf[tid] = v;
    __syncthreads();
    for (int off = 1; off < SCAN_BLK; off <<= 1) {
        int t = (tid >= off) ? buf[tid - off] : 0;
        __syncthreads();
        buf[tid] += t;
        __syncthreads();
    }
    if (i < NN) offsets[i] = buf[tid] - v;   // exclusive
    if (tid == SCAN_BLK - 1) blocksums[blk] = buf[tid];
}

__global__ void k_scan2(int* __restrict__ blocksums, int* __restrict__ offsets) {
    if (threadIdx.x == 0) {
        int run = 0;
        for (int b = 0; b < SCAN_GRID; ++b) {
            int v = blocksums[b];
            blocksums[b] = run;
            run += v;
        }
        offsets[NN] = run;   // = TOT_EDGES
    }
}

__global__ void k_scan3(int* __restrict__ offsets, int* __restrict__ cursors,
                        const int* __restrict__ blocksums) {
    int tid = threadIdx.x, blk = blockIdx.x;
    int i = blk * SCAN_BLK + tid;
    if (i < NN) {
        int o = offsets[i] + blocksums[blk];
        offsets[i] = o;
        cursors[i] = o;
    }
}

__global__ void k_scatter_part(const int* __restrict__ src, const int* __restrict__ dst,
                               int* __restrict__ cursors, int* __restrict__ ssrc) {
    int part = blockIdx.x & (NPART - 1);
    int chunk = blockIdx.x >> 3;
    int lo = part * PART_NODES, hi = lo + PART_NODES;
    int base = chunk * CSR_CHUNK + threadIdx.x;
#pragma unroll
    for (int e = 0; e < CSR_EPT; ++e) {
        int i = base + e * 256;
        if (i < TOT_EDGES) {
            int d = (i < EE) ? dst[i] : (i - EE);
            if (d >= lo && d < hi) {
                int s = (i < EE) ? src[i] : d;
                int idx = atomicAdd(&cursors[d], 1);
                ssrc[idx] = s;
            }
        }
    }
}

// ---------------- prep: wa[in] = sum_out W[in][out]*a[out] per layer ----------------

__global__ void k_prep(const float* __restrict__ W1,
                       const float* __restrict__ as1, const float* __restrict__ ad1,
                       const float* __restrict__ Wh,
                       const float* __restrict__ ash, const float* __restrict__ adh,
                       const float* __restrict__ W2,
                       const float* __restrict__ as2, const float* __restrict__ ad2,
                       float* __restrict__ wa) {
    int t = threadIdx.x;   // 64
    if (t < FD) {
        float s = 0.f, d = 0.f;
        for (int o = 0; o < 64; ++o) {
            s += W1[t * 64 + o] * as1[o];
            d += W1[t * 64 + o] * ad1[o];
        }
        wa[OFF_W1AS + t] = s;
        wa[OFF_W1AD + t] = d;
    }
    {
        float s = 0.f, d = 0.f;
        for (int o = 0; o < 64; ++o) {
            s += Wh[t * 64 + o] * ash[o];
            d += Wh[t * 64 + o] * adh[o];
        }
        wa[OFF_WAS2 + t] = s;
        wa[OFF_WAD2 + t] = d;
    }
    {
        float s = 0.f, d = 0.f;
        for (int o = 0; o < 64; ++o) {
            s += Wh[4096 + t * 64 + o] * ash[64 + o];
            d += Wh[4096 + t * 64 + o] * adh[64 + o];
        }
        wa[OFF_WAS3 + t] = s;
        wa[OFF_WAD3 + t] = d;
    }
    {
        float s = 0.f, d = 0.f;
        for (int o = 0; o < 64; ++o) {
            s += W2[t * 64 + o] * as2[o];
            d += W2[t * 64 + o] * ad2[o];
        }
        wa[OFF_WAS4 + t] = s;
        wa[OFF_WAD4 + t] = d;
    }
}

// ---------------- layer 1 attention coefficients + padded x table ----------------

__global__ void k_attn1(const float* __restrict__ x, const float* __restrict__ wa,
                        float4* __restrict__ xpad, float* __restrict__ es,
                        float* __restrict__ ed) {
    int n = blockIdx.x * blockDim.x + threadIdx.x;
    if (n >= NN) return;
    float x0 = x[3 * n], x1 = x[3 * n + 1], x2 = x[3 * n + 2];
    xpad[n] = make_float4(x0, x1, x2, 0.f);
    es[n] = x0 * wa[OFF_W1AS] + x1 * wa[OFF_W1AS + 1] + x2 * wa[OFF_W1AS + 2];
    ed[n] = x0 * wa[OFF_W1AD] + x1 * wa[OFF_W1AD + 1] + x2 * wa[OFF_W1AD + 2];
}

// ---------------- layer 1 aggregate (IN_DIM=3) + projection W1 ----------------
// Edge-per-lane (rows are 16B): one wave per node. Aggregation commutes with
// projection: row = (sum alpha * x_src)/s, then y = row @ W1 + b1, relu ->
// fp16 x2 table; es2/ed2 = relu(y) . (W@a) via butterfly.

__global__ void k_agg1(const float4* __restrict__ xpad,
                       const float* __restrict__ es, const float* __restrict__ ed,
                       const int* __restrict__ offsets, const int* __restrict__ ssrc,
                       const float* __restrict__ W1, const float* __restrict__ b1,
                       const float* __restrict__ wa,
                       __half* __restrict__ xn, float* __restrict__ esn,
                       float* __restrict__ edn) {
    int n = (blockIdx.x * blockDim.x + threadIdx.x) >> 6;
    int lane = threadIdx.x & 63;
    if (n >= NN) return;
    int beg = offsets[n], end = offsets[n + 1];
    float ednv = ed[n];

    float s = 0.f, a0 = 0.f, a1 = 0.f, a2 = 0.f;
    for (int j = beg + lane; j < end; j += 64) {
        int sj = ssrc[j];
        float e = es[sj] + ednv;
        e = (e > 0.f) ? e : NEG_SLOPE * e;
        float p = __expf(e);
        float4 xv = xpad[sj];
        s += p;
        a0 = fmaf(p, xv.x, a0);
        a1 = fmaf(p, xv.y, a1);
        a2 = fmaf(p, xv.z, a2);
    }
    for (int w = 32; w >= 1; w >>= 1) {
        s  += __shfl_xor(s, w);
        a0 += __shfl_xor(a0, w);
        a1 += __shfl_xor(a1, w);
        a2 += __shfl_xor(a2, w);
    }
    float inv = 1.0f / s;
    float y = b1[lane];
    y = fmaf(a0 * inv, W1[lane], y);
    y = fmaf(a1 * inv, W1[64 + lane], y);
    y = fmaf(a2 * inv, W1[128 + lane], y);
    float xv = fmaxf(y, 0.f);
    xn[(size_t)n * 64 + lane] = __float2half(xv);
    float vs = xv * wa[OFF_WAS2 + lane];
    float vd = xv * wa[OFF_WAD2 + lane];
    for (int w = 32; w >= 1; w >>= 1) {
        vs += __shfl_xor(vs, w);
        vd += __shfl_xor(vd, w);
    }
    if (lane == 0) { esn[n] = vs; edn[n] = vd; }
}

// ---------------- hidden/final aggregate (IN=64) + in-wave projection ----------------
// Grid-stride waves (~6 nodes/wave) so the W column (half2[32] in VGPRs) is
// amortized. Gather: 8 edges/iter (grp=lane>>3), c=lane&7 picks 8 fp16 channels
// (16B/lane). After the butterfly every lane has the full pre-projection row as
// v[8]; projection y[lane] = sum_k row[k]*W[k][lane] via 64 shfl broadcasts.
// FINAL=0: x_next=relu(y+b) -> fp16 table + es/ed of the NEXT layer.
// FINAL=1: y+b -> fp32 d_out.
template<int FINAL>
__launch_bounds__(256, 6)
__global__ void k_agg_h(const __half* __restrict__ xt,
                        const float* __restrict__ es, const float* __restrict__ ed,
                        const int* __restrict__ offsets, const int* __restrict__ ssrc,
                        const float* __restrict__ Wn, const float* __restrict__ bias,
                        const float* __restrict__ wasn, const float* __restrict__ wadn,
                        __half* __restrict__ xn, float* __restrict__ esn,
                        float* __restrict__ edn_out, float* __restrict__ outF,
                        int nwaves_total) {
    int lane = threadIdx.x & 63;
    int wid = (blockIdx.x * blockDim.x + threadIdx.x) >> 6;
    int grp = lane >> 3;
    int c   = lane & 7;

    __half2 wn[32];
#pragma unroll
    for (int q = 0; q < 32; ++q)
        wn[q] = __floats2half2_rn(Wn[(2 * q) * 64 + lane], Wn[(2 * q + 1) * 64 + lane]);
    float bl = bias[lane];
    float wsl = FINAL ? 0.f : wasn[lane];
    float wdl = FINAL ? 0.f : wadn[lane];

    for (int n = wid; n < NN; n += nwaves_total) {
        int beg = offsets[n], end = offsets[n + 1];
        float ednv = ed[n];
        float s = 0.f;
        float acc[8];
#pragma unroll
        for (int i = 0; i < 8; ++i) acc[i] = 0.f;

        for (int j0 = beg; j0 < end; j0 += 8) {
            int jg = j0 + grp;
            if (jg < end) {
                int sj = ssrc[jg];
                float e = es[sj] + ednv;
                e = (e > 0.f) ? e : NEG_SLOPE * e;
                float p = __expf(e);
                s += p;
                float4 raw = *(const float4*)&xt[(size_t)sj * 64 + c * 8];
                const __half2* hp = (const __half2*)&raw;
#pragma unroll
                for (int q = 0; q < 4; ++q) {
                    float2 f = __half22float2(hp[q]);
                    acc[2 * q]     = fmaf(p, f.x, acc[2 * q]);
                    acc[2 * q + 1] = fmaf(p, f.y, acc[2 * q + 1]);
                }
            }
        }
#pragma unroll
        for (int w = 8; w <= 32; w <<= 1) {
            s += __shfl_xor(s, w);
#pragma unroll
            for (int i = 0; i < 8; ++i) acc[i] += __shfl_xor(acc[i], w);
        }
        float inv = 1.0f / s;
        float v[8];
#pragma unroll
        for (int i = 0; i < 8; ++i) v[i] = acc[i] * inv;

        // projection: row[k] lives in v[k&7] on lanes with lane&7 == k>>3
        float y = bl;
#pragma unroll
        for (int j = 0; j < 32; ++j) {
            float2 wf = __half22float2(wn[j]);
            float r0 = __shfl(v[(2 * j) & 7], j >> 2);
            float r1 = __shfl(v[(2 * j + 1) & 7], j >> 2);
            y = fmaf(r0, wf.x, y);
            y = fmaf(r1, wf.y, y);
        }

        if (FINAL) {
            outF[(size_t)n * 64 + lane] = y;
        } else {
            float xv = fmaxf(y, 0.f);
            xn[(size_t)n * 64 + lane] = __float2half(xv);
            float vs = xv * wsl;
            float vd = xv * wdl;
            for (int w = 32; w >= 1; w >>= 1) {
                vs += __shfl_xor(vs, w);
                vd += __shfl_xor(vd, w);
            }
            if (lane == 0) { esn[n] = vs; edn_out[n] = vd; }
        }
    }
}

// ---------------- epilogue ----------------

__global__ void k_pool1(const float* __restrict__ h, float* __restrict__ partial) {
    int blk = blockIdx.x;
    int g = blk / POOL_CHUNKS, c = blk % POOL_CHUNKS;
    int wave = threadIdx.x >> 6, lane = threadIdx.x & 63;
    int base = g * NODES_PER_GRAPH + c * POOL_NODES_PER_CHUNK;
    float acc = 0.f;
    for (int i = wave; i < POOL_NODES_PER_CHUNK; i += 4)
        acc += h[(size_t)(base + i) * 64 + lane];
    __shared__ float buf[4][64];
    buf[wave][lane] = acc;
    __syncthreads();
    if (wave == 0)
        partial[blk * 64 + lane] = buf[0][lane] + buf[1][lane] + buf[2][lane] + buf[3][lane];
}

__global__ void k_pool2(const float* __restrict__ partial, float* __restrict__ pooled) {
    int g = blockIdx.x;
    int lane = threadIdx.x;  // 64
    float acc = 0.f;
    for (int c = 0; c < POOL_CHUNKS; ++c)
        acc += partial[(g * POOL_CHUNKS + c) * 64 + lane];
    pooled[g * 64 + lane] = acc * (1.0f / NODES_PER_GRAPH);
}

__global__ void k_value(const float* __restrict__ pooled,
                        const float* __restrict__ Wv1, const float* __restrict__ bv1,
                        const float* __restrict__ Wv2, const float* __restrict__ bv2,
                        float* __restrict__ value) {
    int g = blockIdx.x;
    int j = threadIdx.x;   // 512
    __shared__ float pl[64];
    if (j < 64) pl[j] = pooled[g * 64 + j];
    __syncthreads();
    float acc = bv1[j];
    for (int c = 0; c < 64; ++c) acc += pl[c] * Wv1[c * 512 + j];
    acc = fmaxf(acc, 0.f);
    float t = acc * Wv2[j];
    for (int w = 32; w >= 1; w >>= 1) t += __shfl_xor(t, w);
    __shared__ float red[8];
    int wave = j >> 6, lane = j & 63;
    if (lane == 0) red[wave] = t;
    __syncthreads();
    if (j == 0) {
        float v = 0.f;
        for (int w = 0; w < 8; ++w) v += red[w];
        value[g] = v + bv2[0];
    }
}

// ---------------- launcher ----------------

extern "C" void kernel_launch(void* const* d_in, const int* in_sizes, int n_in,
                              void* d_out, int out_size, void* d_ws, size_t ws_size,
                              hipStream_t stream) {
    const float* x   = (const float*)d_in[0];
    const int*   ei  = (const int*)d_in[1];     // (2, E): row0=src, row1=dst
    const float* W1  = (const float*)d_in[2];
    const float* as1 = (const float*)d_in[3];
    const float* ad1 = (const float*)d_in[4];
    const float* b1  = (const float*)d_in[5];
    const float* Wh  = (const float*)d_in[6];   // (2,64,64)
    const float* ash = (const float*)d_in[7];
    const float* adh = (const float*)d_in[8];
    const float* bh  = (const float*)d_in[9];
    const float* W2  = (const float*)d_in[10];
    const float* as2 = (const float*)d_in[11];
    const float* ad2 = (const float*)d_in[12];
    const float* b2  = (const float*)d_in[13];
    const float* Wv1 = (const float*)d_in[14];
    const float* bv1 = (const float*)d_in[15];
    const float* Wv2 = (const float*)d_in[16];
    const float* bv2 = (const float*)d_in[17];

    const int* e_src = ei;
    const int* e_dst = ei + EE;

    // workspace carve-up (256B aligned)
    char* p = (char*)d_ws;
    auto carve = [&](size_t bytes) {
        char* r = p;
        p += (bytes + 255) & ~(size_t)255;
        return r;
    };
    int*    counts    = (int*)carve(NN * 4);
    int*    offsets   = (int*)carve((NN + 1) * 4);
    int*    cursors   = (int*)carve(NN * 4);
    int*    ssrc      = (int*)carve(TOT_EDGES * 4);
    int*    blocksums = (int*)carve(SCAN_GRID * 4);
    float*  wa        = (float*)carve(WA_FLOATS * 4);
    float4* xpad      = (float4*)carve((size_t)NN * 16);
    __half* bufA      = (__half*)carve((size_t)NN * 64 * 2);   // fp16 boundary tables
    __half* bufB      = (__half*)carve((size_t)NN * 64 * 2);   // (ping-pong)
    float*  esA       = (float*)carve(NN * 4);
    float*  edA       = (float*)carve(NN * 4);
    float*  esB       = (float*)carve(NN * 4);
    float*  edB       = (float*)carve(NN * 4);
    float*  partial   = (float*)carve((size_t)NUM_GRAPHS * POOL_CHUNKS * 64 * 4);

    float* out_h      = (float*)d_out;                 // [N, 64]
    float* out_pooled = out_h + (size_t)NN * 64;       // [10, 64]
    float* out_value  = out_pooled + NUM_GRAPHS * 64;  // [10]

    // CSR build (reused by all 4 layers)
    k_init_counts<<<(NN + 255) / 256, 256, 0, stream>>>(counts);
    k_count_part<<<NPART * CSR_CHUNKS, 256, 0, stream>>>(e_dst, counts);
    k_scan1<<<SCAN_GRID, SCAN_BLK, 0, stream>>>(counts, offsets, blocksums);
    k_scan2<<<1, 64, 0, stream>>>(blocksums, offsets);
    k_scan3<<<SCAN_GRID, SCAN_BLK, 0, stream>>>(offsets, cursors, blocksums);
    k_scatter_part<<<NPART * CSR_CHUNKS, 256, 0, stream>>>(e_src, e_dst, cursors, ssrc);

    const int HBLK = (NN + 3) / 4;                   // 4 waves/block, 1 node/wave
    const int AGG_WAVES = AGG_BLOCKS * 256 / 64;     // 8192

    // prep W@a vectors + layer-1 coefficients/table
    k_prep<<<1, 64, 0, stream>>>(W1, as1, ad1, Wh, ash, adh, W2, as2, ad2, wa);
    k_attn1<<<(NN + 255) / 256, 256, 0, stream>>>(x, wa, xpad, esA, edA);

    // layer 1: gather x (16B rows) -> project W1 -> x2 (bufA), es2/ed2 (B)
    k_agg1<<<HBLK, 256, 0, stream>>>(xpad, esA, edA, offsets, ssrc, W1, b1, wa,
                                     bufA, esB, edB);
    // layer 2: gather x2 -> project Wh0 -> x3 (bufB), es3/ed3 (A)
    k_agg_h<0><<<AGG_BLOCKS, 256, 0, stream>>>(bufA, esB, edB, offsets, ssrc,
                                               Wh, bh, wa + OFF_WAS3, wa + OFF_WAD3,
                                               bufB, esA, edA, nullptr, AGG_WAVES);
    // layer 3: gather x3 -> project Wh1 -> x4 (bufA), es4/ed4 (B)
    k_agg_h<0><<<AGG_BLOCKS, 256, 0, stream>>>(bufB, esA, edA, offsets, ssrc,
                                               Wh + 4096, bh + 64, wa + OFF_WAS4, wa + OFF_WAD4,
                                               bufA, esB, edB, nullptr, AGG_WAVES);
    // layer 4: gather x4 -> project W2 -> fp32 d_out (no relu)
    k_agg_h<1><<<AGG_BLOCKS, 256, 0, stream>>>(bufA, esB, edB, offsets, ssrc,
                                               W2, b2, nullptr, nullptr,
                                               nullptr, nullptr, nullptr, out_h, AGG_WAVES);

    // pooling + value head
    k_pool1<<<NUM_GRAPHS * POOL_CHUNKS, 256, 0, stream>>>(out_h, partial);
    k_pool2<<<NUM_GRAPHS, 64, 0, stream>>>(partial, out_pooled);
    k_value<<<NUM_GRAPHS, 512, 0, stream>>>(out_pooled, Wv1, bv1, Wv2, bv2, out_value);
}

// Round 12
// 280.309 us; speedup vs baseline: 2.0985x; 2.0985x over previous
//
#include <hip/hip_runtime.h>
#include <hip/hip_fp16.h>
#include <math.h>

#define NN 50000
#define EE 800000
#define TOT_EDGES (EE + NN)   // with self loops
#define FD 3
#define C 64
#define FC 512
#define NODES_PER_GRAPH 5000
#define NUM_GRAPHS 10
#define POOL_CHUNKS 40        // 5000 / 125
#define POOL_NODES_PER_CHUNK 125
#define NEG_SLOPE 0.2f

#define SCAN_BLK 1024
#define SCAN_GRID ((NN + SCAN_BLK - 1) / SCAN_BLK)   // 49

#define HC_BLOCKS 1024        // 4096 waves, ~12 nodes/wave

// XCD-range-partitioned CSR build (see R5): keeps each XCD's scatter footprint
// L2-resident so line writes coalesce in L2 instead of 64B-per-edge HBM writebacks.
#define NPART 8
#define PART_NODES ((NN + NPART - 1) / NPART)        // 6250
#define CSR_EPT 8
#define CSR_CHUNK (256 * CSR_EPT)                    // 2048 edges / block
#define CSR_CHUNKS ((TOT_EDGES + CSR_CHUNK - 1) / CSR_CHUNK)

// ---------------- CSR build ----------------

__global__ void k_init_counts(int* counts) {
    int i = blockIdx.x * blockDim.x + threadIdx.x;
    if (i < NN) counts[i] = 0;   // self loops folded into partitioned count
}

__global__ void k_count_part(const int* __restrict__ dst, int* __restrict__ counts) {
    int part = blockIdx.x & (NPART - 1);
    int chunk = blockIdx.x >> 3;
    int lo = part * PART_NODES, hi = lo + PART_NODES;
    int base = chunk * CSR_CHUNK + threadIdx.x;
#pragma unroll
    for (int e = 0; e < CSR_EPT; ++e) {
        int i = base + e * 256;
        if (i < TOT_EDGES) {
            int d = (i < EE) ? dst[i] : (i - EE);
            if (d >= lo && d < hi) atomicAdd(&counts[d], 1);
        }
    }
}

// stage 1: per-block LDS scan (exclusive within block) + block sums
__global__ void k_scan1(const int* __restrict__ counts, int* __restrict__ offsets,
                        int* __restrict__ blocksums) {
    int tid = threadIdx.x, blk = blockIdx.x;
    int i = blk * SCAN_BLK + tid;
    int v = (i < NN) ? counts[i] : 0;
    __shared__ int buf[SCAN_BLK];
    buf[tid] = v;
    __syncthreads();
    for (int off = 1; off < SCAN_BLK; off <<= 1) {
        int t = (tid >= off) ? buf[tid - off] : 0;
        __syncthreads();
        buf[tid] += t;
        __syncthreads();
    }
    if (i < NN) offsets[i] = buf[tid] - v;   // exclusive
    if (tid == SCAN_BLK - 1) blocksums[blk] = buf[tid];
}

// stage 2: serial scan of 49 block sums (one lane) -> in-place exclusive bases + total
__global__ void k_scan2(int* __restrict__ blocksums, int* __restrict__ offsets) {
    if (threadIdx.x == 0) {
        int run = 0;
        for (int b = 0; b < SCAN_GRID; ++b) {
            int v = blocksums[b];
            blocksums[b] = run;
            run += v;
        }
        offsets[NN] = run;   // = TOT_EDGES
    }
}

// stage 3: add block base, emit cursors
__global__ void k_scan3(int* __restrict__ offsets, int* __restrict__ cursors,
                        const int* __restrict__ blocksums) {
    int tid = threadIdx.x, blk = blockIdx.x;
    int i = blk * SCAN_BLK + tid;
    if (i < NN) {
        int o = offsets[i] + blocksums[blk];
        offsets[i] = o;
        cursors[i] = o;
    }
}

__global__ void k_scatter_part(const int* __restrict__ src, const int* __restrict__ dst,
                               int* __restrict__ cursors, int* __restrict__ ssrc) {
    int part = blockIdx.x & (NPART - 1);
    int chunk = blockIdx.x >> 3;
    int lo = part * PART_NODES, hi = lo + PART_NODES;
    int base = chunk * CSR_CHUNK + threadIdx.x;
#pragma unroll
    for (int e = 0; e < CSR_EPT; ++e) {
        int i = base + e * 256;
        if (i < TOT_EDGES) {
            int d = (i < EE) ? dst[i] : (i - EE);
            if (d >= lo && d < hi) {
                int s = (i < EE) ? src[i] : d;
                int idx = atomicAdd(&cursors[d], 1);
                ssrc[idx] = s;
            }
        }
    }
}

// ---------------- GAT layer kernels ----------------

// Layer-1 projection: h = x @ W1 (FD=3 -> C); es/ed. Wave-per-node grid-stride,
// W column in VGPRs (only 3 here -- fits easily), wave-uniform x-row pointer.
__global__ void k_hcompute_f3(const float* __restrict__ x,
                              const float* __restrict__ W,
                              const float* __restrict__ a_s, const float* __restrict__ a_d,
                              __half* __restrict__ h, float* __restrict__ es,
                              float* __restrict__ ed, int nwaves_total) {
    int lane = threadIdx.x & 63;
    int wid = (blockIdx.x * blockDim.x + threadIdx.x) >> 6;

    float wcol[FD];
#pragma unroll
    for (int k = 0; k < FD; ++k) wcol[k] = W[k * 64 + lane];
    float asl = a_s[lane], adl = a_d[lane];

    for (int n = wid; n < NN; n += nwaves_total) {
        int nu = __builtin_amdgcn_readfirstlane(n);
        const float* xrow = x + (size_t)nu * FD;
        float acc = 0.f;
#pragma unroll
        for (int k = 0; k < FD; ++k) acc = fmaf(xrow[k], wcol[k], acc);
        h[(size_t)nu * 64 + lane] = __float2half(acc);
        float vs = acc * asl;
        float vd = acc * adl;
        for (int w = 32; w >= 1; w >>= 1) {
            vs += __shfl_xor(vs, w);
            vd += __shfl_xor(vd, w);
        }
        if (lane == 0) { es[nu] = vs; ed[nu] = vd; }
    }
}

// Hidden/final projection: h = x16 @ W (C -> C); dedicated kernel (the 64-reg
// W column only fits when it's the sole big register consumer -- R8/R11 lesson).
__global__ void k_hcompute_h64(const __half* __restrict__ x,
                               const float* __restrict__ W,
                               const float* __restrict__ a_s, const float* __restrict__ a_d,
                               __half* __restrict__ h, float* __restrict__ es,
                               float* __restrict__ ed, int nwaves_total) {
    int lane = threadIdx.x & 63;
    int wid = (blockIdx.x * blockDim.x + threadIdx.x) >> 6;

    float wcol[64];
#pragma unroll
    for (int k = 0; k < 64; ++k) wcol[k] = W[k * 64 + lane];
    float asl = a_s[lane], adl = a_d[lane];

    for (int n = wid; n < NN; n += nwaves_total) {
        int nu = __builtin_amdgcn_readfirstlane(n);
        const __half2* xr = (const __half2*)(x + (size_t)nu * 64);
        float acc = 0.f;
#pragma unroll
        for (int q = 0; q < 32; ++q) {
            float2 f = __half22float2(xr[q]);
            acc = fmaf(f.x, wcol[2 * q], acc);
            acc = fmaf(f.y, wcol[2 * q + 1], acc);
        }
        h[(size_t)nu * 64 + lane] = __float2half(acc);
        float vs = acc * asl;
        float vd = acc * adl;
        for (int w = 32; w >= 1; w >>= 1) {
            vs += __shfl_xor(vs, w);
            vd += __shfl_xor(vd, w);
        }
        if (lane == 0) { es[nu] = vs; ed[nu] = vd; }
    }
}

// One wave per dst node, single fused pass (R8/R10 structure), now processing
// 16 edges/iteration: each lane issues TWO independent 16B row-gathers (grp
// picks edges j0+grp and j0+8+grp) -> 2x memory-level parallelism on the
// L2-miss/L3 gather path. Tail edges are predicated (p=0), not branched, so
// both loads always issue. Per-lane accumulation order identical to R10.
template<int HIDDEN>
__global__ void k_aggregate(const __half* __restrict__ h,
                            const float* __restrict__ es, const float* __restrict__ ed,
                            const int* __restrict__ offsets, const int* __restrict__ ssrc,
                            const float* __restrict__ bias,
                            __half* __restrict__ outH, float* __restrict__ outF) {
    int gtid = blockIdx.x * blockDim.x + threadIdx.x;
    int n = gtid >> 6;
    int lane = threadIdx.x & 63;
    if (n >= NN) return;
    int beg = offsets[n], end = offsets[n + 1];
    float ednv = ed[n];

    int grp = lane >> 3;        // 0..7 : which edge of the group
    int c   = lane & 7;         // channel block: halves [8c, 8c+8)
    float s = 0.f;
    float acc[8];
#pragma unroll
    for (int i = 0; i < 8; ++i) acc[i] = 0.f;

    for (int j0 = beg; j0 < end; j0 += 16) {
        int jg0 = j0 + grp;
        int jg1 = j0 + 8 + grp;
        bool v0 = jg0 < end, v1 = jg1 < end;
        int sj0 = v0 ? ssrc[jg0] : 0;
        int sj1 = v1 ? ssrc[jg1] : 0;
        // issue both row loads back-to-back (independent, 2x outstanding)
        float4 raw0 = *(const float4*)&h[(size_t)sj0 * 64 + c * 8];
        float4 raw1 = *(const float4*)&h[(size_t)sj1 * 64 + c * 8];
        float e0 = es[sj0] + ednv;
        float e1 = es[sj1] + ednv;
        e0 = (e0 > 0.f) ? e0 : NEG_SLOPE * e0;
        e1 = (e1 > 0.f) ? e1 : NEG_SLOPE * e1;
        float p0 = v0 ? __expf(e0) : 0.f;
        float p1 = v1 ? __expf(e1) : 0.f;
        s += p0;
        const __half2* hp0 = (const __half2*)&raw0;
#pragma unroll
        for (int q = 0; q < 4; ++q) {
            float2 f = __half22float2(hp0[q]);
            acc[2 * q]     = fmaf(p0, f.x, acc[2 * q]);
            acc[2 * q + 1] = fmaf(p0, f.y, acc[2 * q + 1]);
        }
        s += p1;
        const __half2* hp1 = (const __half2*)&raw1;
#pragma unroll
        for (int q = 0; q < 4; ++q) {
            float2 f = __half22float2(hp1[q]);
            acc[2 * q]     = fmaf(p1, f.x, acc[2 * q]);
            acc[2 * q + 1] = fmaf(p1, f.y, acc[2 * q + 1]);
        }
    }
    // reduce s and acc across the 8 edge-groups (lanes c, c+8, ..., c+56)
#pragma unroll
    for (int w = 8; w <= 32; w <<= 1) {
        s += __shfl_xor(s, w);
#pragma unroll
        for (int i = 0; i < 8; ++i) acc[i] += __shfl_xor(acc[i], w);
    }
    if (grp == 0) {
        float inv_s = 1.0f / s;
        float v[8];
#pragma unroll
        for (int i = 0; i < 8; ++i) {
            v[i] = acc[i] * inv_s + bias[c * 8 + i];
            if (HIDDEN) v[i] = fmaxf(v[i], 0.f);
        }
        if (HIDDEN) {
            __half2 hv[4];
#pragma unroll
            for (int q = 0; q < 4; ++q)
                hv[q] = __floats2half2_rn(v[2 * q], v[2 * q + 1]);
            *(float4*)&outH[(size_t)n * 64 + c * 8] = *(float4*)hv;   // 16B
        } else {
            *(float4*)&outF[(size_t)n * 64 + c * 8]     = make_float4(v[0], v[1], v[2], v[3]);
            *(float4*)&outF[(size_t)n * 64 + c * 8 + 4] = make_float4(v[4], v[5], v[6], v[7]);
        }
    }
}

// ---------------- epilogue ----------------

__global__ void k_pool1(const float* __restrict__ h, float* __restrict__ partial) {
    int blk = blockIdx.x;
    int g = blk / POOL_CHUNKS, c = blk % POOL_CHUNKS;
    int wave = threadIdx.x >> 6, lane = threadIdx.x & 63;
    int base = g * NODES_PER_GRAPH + c * POOL_NODES_PER_CHUNK;
    float acc = 0.f;
    for (int i = wave; i < POOL_NODES_PER_CHUNK; i += 4)
        acc += h[(size_t)(base + i) * 64 + lane];
    __shared__ float buf[4][64];
    buf[wave][lane] = acc;
    __syncthreads();
    if (wave == 0)
        partial[blk * 64 + lane] = buf[0][lane] + buf[1][lane] + buf[2][lane] + buf[3][lane];
}

__global__ void k_pool2(const float* __restrict__ partial, float* __restrict__ pooled) {
    int g = blockIdx.x;
    int lane = threadIdx.x;  // 64
    float acc = 0.f;
    for (int c = 0; c < POOL_CHUNKS; ++c)
        acc += partial[(g * POOL_CHUNKS + c) * 64 + lane];
    pooled[g * 64 + lane] = acc * (1.0f / NODES_PER_GRAPH);
}

__global__ void k_value(const float* __restrict__ pooled,
                        const float* __restrict__ Wv1, const float* __restrict__ bv1,
                        const float* __restrict__ Wv2, const float* __restrict__ bv2,
                        float* __restrict__ value) {
    int g = blockIdx.x;
    int j = threadIdx.x;   // 512
    __shared__ float pl[64];
    if (j < 64) pl[j] = pooled[g * 64 + j];
    __syncthreads();
    float acc = bv1[j];
    for (int c = 0; c < 64; ++c) acc += pl[c] * Wv1[c * 512 + j];
    acc = fmaxf(acc, 0.f);
    float t = acc * Wv2[j];
    for (int w = 32; w >= 1; w >>= 1) t += __shfl_xor(t, w);
    __shared__ float red[8];
    int wave = j >> 6, lane = j & 63;
    if (lane == 0) red[wave] = t;
    __syncthreads();
    if (j == 0) {
        float v = 0.f;
        for (int w = 0; w < 8; ++w) v += red[w];
        value[g] = v + bv2[0];
    }
}

// ---------------- launcher ----------------

extern "C" void kernel_launch(void* const* d_in, const int* in_sizes, int n_in,
                              void* d_out, int out_size, void* d_ws, size_t ws_size,
                              hipStream_t stream) {
    const float* x   = (const float*)d_in[0];
    const int*   ei  = (const int*)d_in[1];     // (2, E): row0=src, row1=dst
    const float* W1  = (const float*)d_in[2];
    const float* as1 = (const float*)d_in[3];
    const float* ad1 = (const float*)d_in[4];
    const float* b1  = (const float*)d_in[5];
    const float* Wh  = (const float*)d_in[6];   // (2,64,64)
    const float* ash = (const float*)d_in[7];
    const float* adh = (const float*)d_in[8];
    const float* bh  = (const float*)d_in[9];
    const float* W2  = (const float*)d_in[10];
    const float* as2 = (const float*)d_in[11];
    const float* ad2 = (const float*)d_in[12];
    const float* b2  = (const float*)d_in[13];
    const float* Wv1 = (const float*)d_in[14];
    const float* bv1 = (const float*)d_in[15];
    const float* Wv2 = (const float*)d_in[16];
    const float* bv2 = (const float*)d_in[17];

    const int* e_src = ei;
    const int* e_dst = ei + EE;

    // workspace carve-up (256B aligned)
    char* p = (char*)d_ws;
    auto carve = [&](size_t bytes) {
        char* r = p;
        p += (bytes + 255) & ~(size_t)255;
        return r;
    };
    int*    counts    = (int*)carve(NN * 4);
    int*    offsets   = (int*)carve((NN + 1) * 4);
    int*    cursors   = (int*)carve(NN * 4);
    int*    ssrc      = (int*)carve(TOT_EDGES * 4);
    int*    blocksums = (int*)carve(SCAN_GRID * 4);
    __half* bufH      = (__half*)carve((size_t)NN * 64 * 2);   // fp16 gather table
    __half* bufB16    = (__half*)carve((size_t)NN * 64 * 2);   // fp16 layer boundary
    float*  es        = (float*)carve(NN * 4);
    float*  ed        = (float*)carve(NN * 4);
    float*  partial   = (float*)carve((size_t)NUM_GRAPHS * POOL_CHUNKS * 64 * 4);

    float* out_h      = (float*)d_out;                 // [N, 64]
    float* out_pooled = out_h + (size_t)NN * 64;       // [10, 64]
    float* out_value  = out_pooled + NUM_GRAPHS * 64;  // [10]

    // CSR build (reused by all 4 layers)
    k_init_counts<<<(NN + 255) / 256, 256, 0, stream>>>(counts);
    k_count_part<<<NPART * CSR_CHUNKS, 256, 0, stream>>>(e_dst, counts);
    k_scan1<<<SCAN_GRID, SCAN_BLK, 0, stream>>>(counts, offsets, blocksums);
    k_scan2<<<1, 64, 0, stream>>>(blocksums, offsets);
    k_scan3<<<SCAN_GRID, SCAN_BLK, 0, stream>>>(offsets, cursors, blocksums);
    k_scatter_part<<<NPART * CSR_CHUNKS, 256, 0, stream>>>(e_src, e_dst, cursors, ssrc);

    const int HBLK = (NN + 3) / 4;             // aggregate: 4 waves/block, 1 node/wave
    const int HC_WAVES = HC_BLOCKS * 256 / 64; // 4096

    // layer 1: FD -> C, relu; boundary buffer is fp16
    k_hcompute_f3<<<HC_BLOCKS, 256, 0, stream>>>(x, W1, as1, ad1, bufH, es, ed, HC_WAVES);
    k_aggregate<1><<<HBLK, 256, 0, stream>>>(bufH, es, ed, offsets, ssrc, b1, bufB16, nullptr);

    // hidden layers: C -> C, relu
    for (int i = 0; i < 2; ++i) {
        k_hcompute_h64<<<HC_BLOCKS, 256, 0, stream>>>(bufB16, Wh + i * 64 * 64, ash + i * 64,
                                                      adh + i * 64, bufH, es, ed, HC_WAVES);
        k_aggregate<1><<<HBLK, 256, 0, stream>>>(bufH, es, ed, offsets, ssrc, bh + i * 64,
                                                 bufB16, nullptr);
    }

    // layer 4: C -> OUT, no relu, write straight to d_out (fp32)
    k_hcompute_h64<<<HC_BLOCKS, 256, 0, stream>>>(bufB16, W2, as2, ad2, bufH, es, ed, HC_WAVES);
    k_aggregate<0><<<HBLK, 256, 0, stream>>>(bufH, es, ed, offsets, ssrc, b2, nullptr, out_h);

    // pooling + value head
    k_pool1<<<NUM_GRAPHS * POOL_CHUNKS, 256, 0, stream>>>(out_h, partial);
    k_pool2<<<NUM_GRAPHS, 64, 0, stream>>>(partial, out_pooled);
    k_value<<<NUM_GRAPHS, 512, 0, stream>>>(out_pooled, Wv1, bv1, Wv2, bv2, out_value);
}

// Round 13
// 255.941 us; speedup vs baseline: 2.2983x; 1.0952x over previous
//
#include <hip/hip_runtime.h>
#include <hip/hip_fp16.h>
#include <math.h>

#define NN 50000
#define EE 800000
#define TOT_EDGES (EE + NN)   // with self loops
#define FD 3
#define C 64
#define FC 512
#define NODES_PER_GRAPH 5000
#define NUM_GRAPHS 10
#define POOL_CHUNKS 40        // 5000 / 125
#define POOL_NODES_PER_CHUNK 125
#define NEG_SLOPE 0.2f

#define SCAN_BLK 1024
#define SCAN_GRID ((NN + SCAN_BLK - 1) / SCAN_BLK)   // 49

#define HC_BLOCKS 1024        // layer-1 scalar hcompute: 4096 waves

#define STRIPES (NN / 16)     // 3125 MFMA row-stripes (50000 % 16 == 0)
#define MFMA_BLOCKS ((STRIPES + 3) / 4)

// XCD-range-partitioned CSR build (see R5): keeps each XCD's scatter footprint
// L2-resident so line writes coalesce in L2 instead of 64B-per-edge HBM writebacks.
#define NPART 8
#define PART_NODES ((NN + NPART - 1) / NPART)        // 6250
#define CSR_EPT 8
#define CSR_CHUNK (256 * CSR_EPT)                    // 2048 edges / block
#define CSR_CHUNKS ((TOT_EDGES + CSR_CHUNK - 1) / CSR_CHUNK)

typedef _Float16 f16x8 __attribute__((ext_vector_type(8)));
typedef float f32x4 __attribute__((ext_vector_type(4)));

// ---------------- CSR build ----------------

__global__ void k_init_counts(int* counts) {
    int i = blockIdx.x * blockDim.x + threadIdx.x;
    if (i < NN) counts[i] = 0;   // self loops folded into partitioned count
}

__global__ void k_count_part(const int* __restrict__ dst, int* __restrict__ counts) {
    int part = blockIdx.x & (NPART - 1);
    int chunk = blockIdx.x >> 3;
    int lo = part * PART_NODES, hi = lo + PART_NODES;
    int base = chunk * CSR_CHUNK + threadIdx.x;
#pragma unroll
    for (int e = 0; e < CSR_EPT; ++e) {
        int i = base + e * 256;
        if (i < TOT_EDGES) {
            int d = (i < EE) ? dst[i] : (i - EE);
            if (d >= lo && d < hi) atomicAdd(&counts[d], 1);
        }
    }
}

// stage 1: per-block LDS scan (exclusive within block) + block sums
__global__ void k_scan1(const int* __restrict__ counts, int* __restrict__ offsets,
                        int* __restrict__ blocksums) {
    int tid = threadIdx.x, blk = blockIdx.x;
    int i = blk * SCAN_BLK + tid;
    int v = (i < NN) ? counts[i] : 0;
    __shared__ int buf[SCAN_BLK];
    buf[tid] = v;
    __syncthreads();
    for (int off = 1; off < SCAN_BLK; off <<= 1) {
        int t = (tid >= off) ? buf[tid - off] : 0;
        __syncthreads();
        buf[tid] += t;
        __syncthreads();
    }
    if (i < NN) offsets[i] = buf[tid] - v;   // exclusive
    if (tid == SCAN_BLK - 1) blocksums[blk] = buf[tid];
}

// stage 2: serial scan of 49 block sums (one lane)
__global__ void k_scan2(int* __restrict__ blocksums, int* __restrict__ offsets) {
    if (threadIdx.x == 0) {
        int run = 0;
        for (int b = 0; b < SCAN_GRID; ++b) {
            int v = blocksums[b];
            blocksums[b] = run;
            run += v;
        }
        offsets[NN] = run;   // = TOT_EDGES
    }
}

// stage 3: add block base, emit cursors
__global__ void k_scan3(int* __restrict__ offsets, int* __restrict__ cursors,
                        const int* __restrict__ blocksums) {
    int tid = threadIdx.x, blk = blockIdx.x;
    int i = blk * SCAN_BLK + tid;
    if (i < NN) {
        int o = offsets[i] + blocksums[blk];
        offsets[i] = o;
        cursors[i] = o;
    }
}

__global__ void k_scatter_part(const int* __restrict__ src, const int* __restrict__ dst,
                               int* __restrict__ cursors, int* __restrict__ ssrc) {
    int part = blockIdx.x & (NPART - 1);
    int chunk = blockIdx.x >> 3;
    int lo = part * PART_NODES, hi = lo + PART_NODES;
    int base = chunk * CSR_CHUNK + threadIdx.x;
#pragma unroll
    for (int e = 0; e < CSR_EPT; ++e) {
        int i = base + e * 256;
        if (i < TOT_EDGES) {
            int d = (i < EE) ? dst[i] : (i - EE);
            if (d >= lo && d < hi) {
                int s = (i < EE) ? src[i] : d;
                int idx = atomicAdd(&cursors[d], 1);
                ssrc[idx] = s;
            }
        }
    }
}

// ---------------- W fragment packing (for MFMA projections) ----------------
// wpack layout: [layer(3)][frag(8)][lane(64)][j(8)] halves; frag f = t*2+h,
// t = output col-tile (0..3), h = K-half (0..1).
// B-fragment mapping (K=32 x N=16): lane l -> col = l&15, k = (l>>4)*8 + j.
__global__ void k_wpack(const float* __restrict__ Wh, const float* __restrict__ W2,
                        __half* __restrict__ wpack) {
    int tid = blockIdx.x * blockDim.x + threadIdx.x;
    if (tid >= 3 * 8 * 64) return;
    int l = tid & 63, f = (tid >> 6) & 7, layer = tid >> 9;
    const float* W = (layer == 0) ? Wh : (layer == 1) ? (Wh + 4096) : W2;
    int t = f >> 1, h = f & 1;
#pragma unroll
    for (int j = 0; j < 8; ++j) {
        float w = W[(h * 32 + (l >> 4) * 8 + j) * 64 + (t * 16 + (l & 15))];
        wpack[(size_t)tid * 8 + j] = __float2half(w);
    }
}

// ---------------- GAT layer kernels ----------------

// Layer-1 projection: h = x @ W1 (FD=3 -> C); es/ed. Scalar path (K=3 too small
// for MFMA). Wave-per-node grid-stride, W column in VGPRs, wave-uniform x-row.
__global__ void k_hcompute_f3(const float* __restrict__ x,
                              const float* __restrict__ W,
                              const float* __restrict__ a_s, const float* __restrict__ a_d,
                              __half* __restrict__ h, float* __restrict__ es,
                              float* __restrict__ ed, int nwaves_total) {
    int lane = threadIdx.x & 63;
    int wid = (blockIdx.x * blockDim.x + threadIdx.x) >> 6;

    float wcol[FD];
#pragma unroll
    for (int k = 0; k < FD; ++k) wcol[k] = W[k * 64 + lane];
    float asl = a_s[lane], adl = a_d[lane];

    for (int n = wid; n < NN; n += nwaves_total) {
        int nu = __builtin_amdgcn_readfirstlane(n);
        const float* xrow = x + (size_t)nu * FD;
        float acc = 0.f;
#pragma unroll
        for (int k = 0; k < FD; ++k) acc = fmaf(xrow[k], wcol[k], acc);
        h[(size_t)nu * 64 + lane] = __float2half(acc);
        float vs = acc * asl;
        float vd = acc * adl;
        for (int w = 32; w >= 1; w >>= 1) {
            vs += __shfl_xor(vs, w);
            vd += __shfl_xor(vd, w);
        }
        if (lane == 0) { es[nu] = vs; ed[nu] = vd; }
    }
}

// Hidden/final projection as MFMA GEMM: H[n][o] = sum_k X[n][k] * W[k][o],
// X fp16 [NN][64], W pre-packed fp16 fragments. One wave = 16-row x 64-col
// stripe: 4 col-tiles x 2 K-halves = 8x mfma_f32_16x16x32_f16.
// A-fragment: lane l -> row = l&15, k = (l>>4)*8+j (16B load from X).
// C/D (m89-verified): col = lane&15, row = (lane>>4)*4 + reg.
// es/ed folded in: per-tile scale by a_s/a_d[col], butterfly over 16 col-lanes.
__global__ void k_hc_mfma(const __half* __restrict__ X,
                          const __half* __restrict__ wpack,   // this layer's 8 frags
                          const float* __restrict__ a_s, const float* __restrict__ a_d,
                          __half* __restrict__ H, float* __restrict__ es,
                          float* __restrict__ ed) {
    int lane = threadIdx.x & 63;
    int stripe = (blockIdx.x * blockDim.x + threadIdx.x) >> 6;
    if (stripe >= STRIPES) return;
    int rowbase = stripe * 16;
    int lr = lane & 15, lg = lane >> 4;

    // B fragments (one 16B load each, L2-resident)
    f16x8 b[8];
    const float4* wp = (const float4*)wpack;
#pragma unroll
    for (int f = 0; f < 8; ++f) {
        float4 raw = wp[f * 64 + lane];
        b[f] = *(const f16x8*)&raw;
    }
    // A fragments: two K-halves
    const __half* xrow = X + (size_t)(rowbase + lr) * 64 + lg * 8;
    float4 a0raw = *(const float4*)xrow;
    float4 a1raw = *(const float4*)(xrow + 32);
    f16x8 a0 = *(const f16x8*)&a0raw;
    f16x8 a1 = *(const f16x8*)&a1raw;

    float esa[4] = {0.f, 0.f, 0.f, 0.f};
    float eda[4] = {0.f, 0.f, 0.f, 0.f};
#pragma unroll
    for (int t = 0; t < 4; ++t) {
        f32x4 acc = {0.f, 0.f, 0.f, 0.f};
        acc = __builtin_amdgcn_mfma_f32_16x16x32_f16(a0, b[t * 2], acc, 0, 0, 0);
        acc = __builtin_amdgcn_mfma_f32_16x16x32_f16(a1, b[t * 2 + 1], acc, 0, 0, 0);
        float asv = a_s[t * 16 + lr];
        float adv = a_d[t * 16 + lr];
#pragma unroll
        for (int r = 0; r < 4; ++r) {
            float v = acc[r];
            H[(size_t)(rowbase + lg * 4 + r) * 64 + t * 16 + lr] = __float2half(v);
            esa[r] = fmaf(v, asv, esa[r]);
            eda[r] = fmaf(v, adv, eda[r]);
        }
    }
    // reduce across the 16 col-lanes (xor bits 0..3 stay within lg group)
#pragma unroll
    for (int w = 1; w <= 8; w <<= 1) {
#pragma unroll
        for (int r = 0; r < 4; ++r) {
            esa[r] += __shfl_xor(esa[r], w);
            eda[r] += __shfl_xor(eda[r], w);
        }
    }
    if (lr == 0) {
#pragma unroll
        for (int r = 0; r < 4; ++r) {
            es[rowbase + lg * 4 + r] = esa[r];
            ed[rowbase + lg * 4 + r] = eda[r];
        }
    }
}

// One wave per dst node, single fused pass, 16 edges/iteration (R12 structure).
template<int HIDDEN>
__global__ void k_aggregate(const __half* __restrict__ h,
                            const float* __restrict__ es, const float* __restrict__ ed,
                            const int* __restrict__ offsets, const int* __restrict__ ssrc,
                            const float* __restrict__ bias,
                            __half* __restrict__ outH, float* __restrict__ outF) {
    int gtid = blockIdx.x * blockDim.x + threadIdx.x;
    int n = gtid >> 6;
    int lane = threadIdx.x & 63;
    if (n >= NN) return;
    int beg = offsets[n], end = offsets[n + 1];
    float ednv = ed[n];

    int grp = lane >> 3;        // 0..7 : which edge of the group
    int c   = lane & 7;         // channel block: halves [8c, 8c+8)
    float s = 0.f;
    float acc[8];
#pragma unroll
    for (int i = 0; i < 8; ++i) acc[i] = 0.f;

    for (int j0 = beg; j0 < end; j0 += 16) {
        int jg0 = j0 + grp;
        int jg1 = j0 + 8 + grp;
        bool v0 = jg0 < end, v1 = jg1 < end;
        int sj0 = v0 ? ssrc[jg0] : 0;
        int sj1 = v1 ? ssrc[jg1] : 0;
        float4 raw0 = *(const float4*)&h[(size_t)sj0 * 64 + c * 8];
        float4 raw1 = *(const float4*)&h[(size_t)sj1 * 64 + c * 8];
        float e0 = es[sj0] + ednv;
        float e1 = es[sj1] + ednv;
        e0 = (e0 > 0.f) ? e0 : NEG_SLOPE * e0;
        e1 = (e1 > 0.f) ? e1 : NEG_SLOPE * e1;
        float p0 = v0 ? __expf(e0) : 0.f;
        float p1 = v1 ? __expf(e1) : 0.f;
        s += p0;
        const __half2* hp0 = (const __half2*)&raw0;
#pragma unroll
        for (int q = 0; q < 4; ++q) {
            float2 f = __half22float2(hp0[q]);
            acc[2 * q]     = fmaf(p0, f.x, acc[2 * q]);
            acc[2 * q + 1] = fmaf(p0, f.y, acc[2 * q + 1]);
        }
        s += p1;
        const __half2* hp1 = (const __half2*)&raw1;
#pragma unroll
        for (int q = 0; q < 4; ++q) {
            float2 f = __half22float2(hp1[q]);
            acc[2 * q]     = fmaf(p1, f.x, acc[2 * q]);
            acc[2 * q + 1] = fmaf(p1, f.y, acc[2 * q + 1]);
        }
    }
#pragma unroll
    for (int w = 8; w <= 32; w <<= 1) {
        s += __shfl_xor(s, w);
#pragma unroll
        for (int i = 0; i < 8; ++i) acc[i] += __shfl_xor(acc[i], w);
    }
    if (grp == 0) {
        float inv_s = 1.0f / s;
        float v[8];
#pragma unroll
        for (int i = 0; i < 8; ++i) {
            v[i] = acc[i] * inv_s + bias[c * 8 + i];
            if (HIDDEN) v[i] = fmaxf(v[i], 0.f);
        }
        if (HIDDEN) {
            __half2 hv[4];
#pragma unroll
            for (int q = 0; q < 4; ++q)
                hv[q] = __floats2half2_rn(v[2 * q], v[2 * q + 1]);
            *(float4*)&outH[(size_t)n * 64 + c * 8] = *(float4*)hv;   // 16B
        } else {
            *(float4*)&outF[(size_t)n * 64 + c * 8]     = make_float4(v[0], v[1], v[2], v[3]);
            *(float4*)&outF[(size_t)n * 64 + c * 8 + 4] = make_float4(v[4], v[5], v[6], v[7]);
        }
    }
}

// ---------------- epilogue ----------------

__global__ void k_pool1(const float* __restrict__ h, float* __restrict__ partial) {
    int blk = blockIdx.x;
    int g = blk / POOL_CHUNKS, c = blk % POOL_CHUNKS;
    int wave = threadIdx.x >> 6, lane = threadIdx.x & 63;
    int base = g * NODES_PER_GRAPH + c * POOL_NODES_PER_CHUNK;
    float acc = 0.f;
    for (int i = wave; i < POOL_NODES_PER_CHUNK; i += 4)
        acc += h[(size_t)(base + i) * 64 + lane];
    __shared__ float buf[4][64];
    buf[wave][lane] = acc;
    __syncthreads();
    if (wave == 0)
        partial[blk * 64 + lane] = buf[0][lane] + buf[1][lane] + buf[2][lane] + buf[3][lane];
}

__global__ void k_pool2(const float* __restrict__ partial, float* __restrict__ pooled) {
    int g = blockIdx.x;
    int lane = threadIdx.x;  // 64
    float acc = 0.f;
    for (int c = 0; c < POOL_CHUNKS; ++c)
        acc += partial[(g * POOL_CHUNKS + c) * 64 + lane];
    pooled[g * 64 + lane] = acc * (1.0f / NODES_PER_GRAPH);
}

__global__ void k_value(const float* __restrict__ pooled,
                        const float* __restrict__ Wv1, const float* __restrict__ bv1,
                        const float* __restrict__ Wv2, const float* __restrict__ bv2,
                        float* __restrict__ value) {
    int g = blockIdx.x;
    int j = threadIdx.x;   // 512
    __shared__ float pl[64];
    if (j < 64) pl[j] = pooled[g * 64 + j];
    __syncthreads();
    float acc = bv1[j];
    for (int c = 0; c < 64; ++c) acc += pl[c] * Wv1[c * 512 + j];
    acc = fmaxf(acc, 0.f);
    float t = acc * Wv2[j];
    for (int w = 32; w >= 1; w >>= 1) t += __shfl_xor(t, w);
    __shared__ float red[8];
    int wave = j >> 6, lane = j & 63;
    if (lane == 0) red[wave] = t;
    __syncthreads();
    if (j == 0) {
        float v = 0.f;
        for (int w = 0; w < 8; ++w) v += red[w];
        value[g] = v + bv2[0];
    }
}

// ---------------- launcher ----------------

extern "C" void kernel_launch(void* const* d_in, const int* in_sizes, int n_in,
                              void* d_out, int out_size, void* d_ws, size_t ws_size,
                              hipStream_t stream) {
    const float* x   = (const float*)d_in[0];
    const int*   ei  = (const int*)d_in[1];     // (2, E): row0=src, row1=dst
    const float* W1  = (const float*)d_in[2];
    const float* as1 = (const float*)d_in[3];
    const float* ad1 = (const float*)d_in[4];
    const float* b1  = (const float*)d_in[5];
    const float* Wh  = (const float*)d_in[6];   // (2,64,64)
    const float* ash = (const float*)d_in[7];
    const float* adh = (const float*)d_in[8];
    const float* bh  = (const float*)d_in[9];
    const float* W2  = (const float*)d_in[10];
    const float* as2 = (const float*)d_in[11];
    const float* ad2 = (const float*)d_in[12];
    const float* b2  = (const float*)d_in[13];
    const float* Wv1 = (const float*)d_in[14];
    const float* bv1 = (const float*)d_in[15];
    const float* Wv2 = (const float*)d_in[16];
    const float* bv2 = (const float*)d_in[17];

    const int* e_src = ei;
    const int* e_dst = ei + EE;

    // workspace carve-up (256B aligned)
    char* p = (char*)d_ws;
    auto carve = [&](size_t bytes) {
        char* r = p;
        p += (bytes + 255) & ~(size_t)255;
        return r;
    };
    int*    counts    = (int*)carve(NN * 4);
    int*    offsets   = (int*)carve((NN + 1) * 4);
    int*    cursors   = (int*)carve(NN * 4);
    int*    ssrc      = (int*)carve(TOT_EDGES * 4);
    int*    blocksums = (int*)carve(SCAN_GRID * 4);
    __half* wpack     = (__half*)carve(3 * 8 * 64 * 8 * 2);    // packed W fragments
    __half* bufH      = (__half*)carve((size_t)NN * 64 * 2);   // fp16 gather table
    __half* bufB16    = (__half*)carve((size_t)NN * 64 * 2);   // fp16 layer boundary
    float*  es        = (float*)carve(NN * 4);
    float*  ed        = (float*)carve(NN * 4);
    float*  partial   = (float*)carve((size_t)NUM_GRAPHS * POOL_CHUNKS * 64 * 4);

    float* out_h      = (float*)d_out;                 // [N, 64]
    float* out_pooled = out_h + (size_t)NN * 64;       // [10, 64]
    float* out_value  = out_pooled + NUM_GRAPHS * 64;  // [10]

    // CSR build (reused by all 4 layers) + W packing
    k_init_counts<<<(NN + 255) / 256, 256, 0, stream>>>(counts);
    k_count_part<<<NPART * CSR_CHUNKS, 256, 0, stream>>>(e_dst, counts);
    k_scan1<<<SCAN_GRID, SCAN_BLK, 0, stream>>>(counts, offsets, blocksums);
    k_scan2<<<1, 64, 0, stream>>>(blocksums, offsets);
    k_scan3<<<SCAN_GRID, SCAN_BLK, 0, stream>>>(offsets, cursors, blocksums);
    k_scatter_part<<<NPART * CSR_CHUNKS, 256, 0, stream>>>(e_src, e_dst, cursors, ssrc);
    k_wpack<<<6, 256, 0, stream>>>(Wh, W2, wpack);

    const int HBLK = (NN + 3) / 4;             // aggregate: 4 waves/block, 1 node/wave
    const int HC_WAVES = HC_BLOCKS * 256 / 64; // 4096
    const int WPL = 8 * 64 * 8;                // wpack halves per layer

    // layer 1: FD -> C (scalar), relu; boundary buffer is fp16
    k_hcompute_f3<<<HC_BLOCKS, 256, 0, stream>>>(x, W1, as1, ad1, bufH, es, ed, HC_WAVES);
    k_aggregate<1><<<HBLK, 256, 0, stream>>>(bufH, es, ed, offsets, ssrc, b1, bufB16, nullptr);

    // hidden layers: C -> C via MFMA, relu in aggregate
    for (int i = 0; i < 2; ++i) {
        k_hc_mfma<<<MFMA_BLOCKS, 256, 0, stream>>>(bufB16, wpack + i * WPL,
                                                   ash + i * 64, adh + i * 64,
                                                   bufH, es, ed);
        k_aggregate<1><<<HBLK, 256, 0, stream>>>(bufH, es, ed, offsets, ssrc, bh + i * 64,
                                                 bufB16, nullptr);
    }

    // layer 4: C -> OUT via MFMA, no relu, write straight to d_out (fp32)
    k_hc_mfma<<<MFMA_BLOCKS, 256, 0, stream>>>(bufB16, wpack + 2 * WPL, as2, ad2,
                                               bufH, es, ed);
    k_aggregate<0><<<HBLK, 256, 0, stream>>>(bufH, es, ed, offsets, ssrc, b2, nullptr, out_h);

    // pooling + value head
    k_pool1<<<NUM_GRAPHS * POOL_CHUNKS, 256, 0, stream>>>(out_h, partial);
    k_pool2<<<NUM_GRAPHS, 64, 0, stream>>>(partial, out_pooled);
    k_value<<<NUM_GRAPHS, 512, 0, stream>>>(out_pooled, Wv1, bv1, Wv2, bv2, out_value);
}

// Round 14
// 252.612 us; speedup vs baseline: 2.3286x; 1.0132x over previous
//
#include <hip/hip_runtime.h>
#include <hip/hip_fp16.h>
#include <math.h>

#define NN 50000
#define EE 800000
#define TOT_EDGES (EE + NN)   // with self loops
#define FD 3
#define C 64
#define FC 512
#define NODES_PER_GRAPH 5000
#define NUM_GRAPHS 10
#define POOL_CHUNKS 40        // 5000 / 125
#define POOL_NODES_PER_CHUNK 125
#define NEG_SLOPE 0.2f

#define SCAN_BLK 1024
#define SCAN_GRID ((NN + SCAN_BLK - 1) / SCAN_BLK)   // 49

#define HC_BLOCKS 1024        // layer-1 scalar hcompute: 4096 waves

#define STRIPES (NN / 16)     // 3125 MFMA row-stripes (50000 % 16 == 0)
#define MFMA_BLOCKS ((STRIPES + 3) / 4)

// XCD-range-partitioned CSR build (see R5): keeps each XCD's scatter footprint
// L2-resident so line writes coalesce in L2 instead of 64B-per-edge HBM writebacks.
#define NPART 8
#define PART_NODES ((NN + NPART - 1) / NPART)        // 6250
#define CSR_EPT 8
#define CSR_CHUNK (256 * CSR_EPT)                    // 2048 edges / block
#define CSR_CHUNKS ((TOT_EDGES + CSR_CHUNK - 1) / CSR_CHUNK)

typedef _Float16 f16x8 __attribute__((ext_vector_type(8)));
typedef float f32x4 __attribute__((ext_vector_type(4)));

// ---------------- CSR build ----------------

__global__ void k_count_part(const int* __restrict__ dst, int* __restrict__ counts) {
    int part = blockIdx.x & (NPART - 1);
    int chunk = blockIdx.x >> 3;
    int lo = part * PART_NODES, hi = lo + PART_NODES;
    int base = chunk * CSR_CHUNK + threadIdx.x;
#pragma unroll
    for (int e = 0; e < CSR_EPT; ++e) {
        int i = base + e * 256;
        if (i < TOT_EDGES) {
            int d = (i < EE) ? dst[i] : (i - EE);
            if (d >= lo && d < hi) atomicAdd(&counts[d], 1);
        }
    }
}

// stage 1: per-block LDS scan (exclusive within block) + block sums
__global__ void k_scan1(const int* __restrict__ counts, int* __restrict__ offsets,
                        int* __restrict__ blocksums) {
    int tid = threadIdx.x, blk = blockIdx.x;
    int i = blk * SCAN_BLK + tid;
    int v = (i < NN) ? counts[i] : 0;
    __shared__ int buf[SCAN_BLK];
    buf[tid] = v;
    __syncthreads();
    for (int off = 1; off < SCAN_BLK; off <<= 1) {
        int t = (tid >= off) ? buf[tid - off] : 0;
        __syncthreads();
        buf[tid] += t;
        __syncthreads();
    }
    if (i < NN) offsets[i] = buf[tid] - v;   // exclusive
    if (tid == SCAN_BLK - 1) blocksums[blk] = buf[tid];
}

// stage 2: serial scan of 49 block sums (one lane)
__global__ void k_scan2(int* __restrict__ blocksums, int* __restrict__ offsets) {
    if (threadIdx.x == 0) {
        int run = 0;
        for (int b = 0; b < SCAN_GRID; ++b) {
            int v = blocksums[b];
            blocksums[b] = run;
            run += v;
        }
        offsets[NN] = run;   // = TOT_EDGES
    }
}

// stage 3: add block base, emit cursors
__global__ void k_scan3(int* __restrict__ offsets, int* __restrict__ cursors,
                        const int* __restrict__ blocksums) {
    int tid = threadIdx.x, blk = blockIdx.x;
    int i = blk * SCAN_BLK + tid;
    if (i < NN) {
        int o = offsets[i] + blocksums[blk];
        offsets[i] = o;
        cursors[i] = o;
    }
}

__global__ void k_scatter_part(const int* __restrict__ src, const int* __restrict__ dst,
                               int* __restrict__ cursors, int* __restrict__ ssrc) {
    int part = blockIdx.x & (NPART - 1);
    int chunk = blockIdx.x >> 3;
    int lo = part * PART_NODES, hi = lo + PART_NODES;
    int base = chunk * CSR_CHUNK + threadIdx.x;
#pragma unroll
    for (int e = 0; e < CSR_EPT; ++e) {
        int i = base + e * 256;
        if (i < TOT_EDGES) {
            int d = (i < EE) ? dst[i] : (i - EE);
            if (d >= lo && d < hi) {
                int s = (i < EE) ? src[i] : d;
                int idx = atomicAdd(&cursors[d], 1);
                ssrc[idx] = s;
            }
        }
    }
}

// ---------------- W fragment packing (for MFMA projections) ----------------
// wpack layout: [layer(3)][frag(8)][lane(64)][j(8)] halves; frag f = t*2+h.
// B-fragment mapping (K=32 x N=16): lane l -> col = l&15, k = (l>>4)*8 + j.
__global__ void k_wpack(const float* __restrict__ Wh, const float* __restrict__ W2,
                        __half* __restrict__ wpack) {
    int tid = blockIdx.x * blockDim.x + threadIdx.x;
    if (tid >= 3 * 8 * 64) return;
    int l = tid & 63, f = (tid >> 6) & 7, layer = tid >> 9;
    const float* W = (layer == 0) ? Wh : (layer == 1) ? (Wh + 4096) : W2;
    int t = f >> 1, h = f & 1;
#pragma unroll
    for (int j = 0; j < 8; ++j) {
        float w = W[(h * 32 + (l >> 4) * 8 + j) * 64 + (t * 16 + (l & 15))];
        wpack[(size_t)tid * 8 + j] = __float2half(w);
    }
}

// ---------------- GAT layer kernels ----------------

// Layer-1 projection: h = x @ W1 (FD=3 -> C); es/ed. Scalar path (K=3).
__global__ void k_hcompute_f3(const float* __restrict__ x,
                              const float* __restrict__ W,
                              const float* __restrict__ a_s, const float* __restrict__ a_d,
                              __half* __restrict__ h, float* __restrict__ es,
                              float* __restrict__ ed, int nwaves_total) {
    int lane = threadIdx.x & 63;
    int wid = (blockIdx.x * blockDim.x + threadIdx.x) >> 6;

    float wcol[FD];
#pragma unroll
    for (int k = 0; k < FD; ++k) wcol[k] = W[k * 64 + lane];
    float asl = a_s[lane], adl = a_d[lane];

    for (int n = wid; n < NN; n += nwaves_total) {
        int nu = __builtin_amdgcn_readfirstlane(n);
        const float* xrow = x + (size_t)nu * FD;
        float acc = 0.f;
#pragma unroll
        for (int k = 0; k < FD; ++k) acc = fmaf(xrow[k], wcol[k], acc);
        h[(size_t)nu * 64 + lane] = __float2half(acc);
        float vs = acc * asl;
        float vd = acc * adl;
        for (int w = 32; w >= 1; w >>= 1) {
            vs += __shfl_xor(vs, w);
            vd += __shfl_xor(vd, w);
        }
        if (lane == 0) { es[nu] = vs; ed[nu] = vd; }
    }
}

// Hidden/final projection as MFMA GEMM (R13, verified): one wave = 16x64 stripe,
// 8x mfma_f32_16x16x32_f16. es/ed folded via per-tile scale + 16-lane butterfly.
__global__ void k_hc_mfma(const __half* __restrict__ X,
                          const __half* __restrict__ wpack,   // this layer's 8 frags
                          const float* __restrict__ a_s, const float* __restrict__ a_d,
                          __half* __restrict__ H, float* __restrict__ es,
                          float* __restrict__ ed) {
    int lane = threadIdx.x & 63;
    int stripe = (blockIdx.x * blockDim.x + threadIdx.x) >> 6;
    if (stripe >= STRIPES) return;
    int rowbase = stripe * 16;
    int lr = lane & 15, lg = lane >> 4;

    f16x8 b[8];
    const float4* wp = (const float4*)wpack;
#pragma unroll
    for (int f = 0; f < 8; ++f) {
        float4 raw = wp[f * 64 + lane];
        b[f] = *(const f16x8*)&raw;
    }
    const __half* xrow = X + (size_t)(rowbase + lr) * 64 + lg * 8;
    float4 a0raw = *(const float4*)xrow;
    float4 a1raw = *(const float4*)(xrow + 32);
    f16x8 a0 = *(const f16x8*)&a0raw;
    f16x8 a1 = *(const f16x8*)&a1raw;

    float esa[4] = {0.f, 0.f, 0.f, 0.f};
    float eda[4] = {0.f, 0.f, 0.f, 0.f};
#pragma unroll
    for (int t = 0; t < 4; ++t) {
        f32x4 acc = {0.f, 0.f, 0.f, 0.f};
        acc = __builtin_amdgcn_mfma_f32_16x16x32_f16(a0, b[t * 2], acc, 0, 0, 0);
        acc = __builtin_amdgcn_mfma_f32_16x16x32_f16(a1, b[t * 2 + 1], acc, 0, 0, 0);
        float asv = a_s[t * 16 + lr];
        float adv = a_d[t * 16 + lr];
#pragma unroll
        for (int r = 0; r < 4; ++r) {
            float v = acc[r];
            H[(size_t)(rowbase + lg * 4 + r) * 64 + t * 16 + lr] = __float2half(v);
            esa[r] = fmaf(v, asv, esa[r]);
            eda[r] = fmaf(v, adv, eda[r]);
        }
    }
#pragma unroll
    for (int w = 1; w <= 8; w <<= 1) {
#pragma unroll
        for (int r = 0; r < 4; ++r) {
            esa[r] += __shfl_xor(esa[r], w);
            eda[r] += __shfl_xor(eda[r], w);
        }
    }
    if (lr == 0) {
#pragma unroll
        for (int r = 0; r < 4; ++r) {
            es[rowbase + lg * 4 + r] = esa[r];
            ed[rowbase + lg * 4 + r] = eda[r];
        }
    }
}

// One wave per dst node, single fused pass. NEW (R14): phase-split per 64-edge
// chunk. Phase A: p computed EDGE-PER-LANE (one es-gather + one exp per edge,
// vs 8x duplicated before). Phase B: p/sj redistributed via __shfl (LDS pipe,
// overlaps VALU); gather structure = R12's 16 edges/iter, 2 independent 16B
// row loads per lane. s reduced by full 64-lane butterfly at the end.
template<int HIDDEN>
__global__ void k_aggregate(const __half* __restrict__ h,
                            const float* __restrict__ es, const float* __restrict__ ed,
                            const int* __restrict__ offsets, const int* __restrict__ ssrc,
                            const float* __restrict__ bias,
                            __half* __restrict__ outH, float* __restrict__ outF) {
    int gtid = blockIdx.x * blockDim.x + threadIdx.x;
    int n = gtid >> 6;
    int lane = threadIdx.x & 63;
    if (n >= NN) return;
    int beg = offsets[n], end = offsets[n + 1];
    float ednv = ed[n];

    int grp = lane >> 3;        // 0..7 : which edge of the group
    int c   = lane & 7;         // channel block: halves [8c, 8c+8)
    float s = 0.f;
    float acc[8];
#pragma unroll
    for (int i = 0; i < 8; ++i) acc[i] = 0.f;

    for (int j0 = beg; j0 < end; j0 += 64) {
        // phase A: edge-per-lane p
        int j = j0 + lane;
        float p = 0.f;
        int sjA = 0;
        if (j < end) {
            sjA = ssrc[j];
            float e = es[sjA] + ednv;
            e = (e > 0.f) ? e : NEG_SLOPE * e;
            p = __expf(e);
        }
        s += p;
        int cnt = end - j0; if (cnt > 64) cnt = 64;
        // phase B: 16 edges per sub-iter, 2 gathers in flight per lane
        for (int sub = 0; sub * 16 < cnt; ++sub) {
            int e0 = sub * 16 + grp;
            int e1 = sub * 16 + 8 + grp;
            float pe0 = __shfl(p, e0);
            float pe1 = __shfl(p, e1);
            int sj0 = __shfl(sjA, e0);
            int sj1 = __shfl(sjA, e1);
            float4 raw0 = *(const float4*)&h[(size_t)sj0 * 64 + c * 8];
            float4 raw1 = *(const float4*)&h[(size_t)sj1 * 64 + c * 8];
            const __half2* hp0 = (const __half2*)&raw0;
#pragma unroll
            for (int q = 0; q < 4; ++q) {
                float2 f = __half22float2(hp0[q]);
                acc[2 * q]     = fmaf(pe0, f.x, acc[2 * q]);
                acc[2 * q + 1] = fmaf(pe0, f.y, acc[2 * q + 1]);
            }
            const __half2* hp1 = (const __half2*)&raw1;
#pragma unroll
            for (int q = 0; q < 4; ++q) {
                float2 f = __half22float2(hp1[q]);
                acc[2 * q]     = fmaf(pe1, f.x, acc[2 * q]);
                acc[2 * q + 1] = fmaf(pe1, f.y, acc[2 * q + 1]);
            }
        }
    }
    // s: full 64-lane butterfly; acc: reduce across the 8 edge-groups
#pragma unroll
    for (int w = 32; w >= 1; w >>= 1) s += __shfl_xor(s, w);
#pragma unroll
    for (int w = 8; w <= 32; w <<= 1) {
#pragma unroll
        for (int i = 0; i < 8; ++i) acc[i] += __shfl_xor(acc[i], w);
    }
    if (grp == 0) {
        float inv_s = 1.0f / s;
        float v[8];
#pragma unroll
        for (int i = 0; i < 8; ++i) {
            v[i] = acc[i] * inv_s + bias[c * 8 + i];
            if (HIDDEN) v[i] = fmaxf(v[i], 0.f);
        }
        if (HIDDEN) {
            __half2 hv[4];
#pragma unroll
            for (int q = 0; q < 4; ++q)
                hv[q] = __floats2half2_rn(v[2 * q], v[2 * q + 1]);
            *(float4*)&outH[(size_t)n * 64 + c * 8] = *(float4*)hv;   // 16B
        } else {
            *(float4*)&outF[(size_t)n * 64 + c * 8]     = make_float4(v[0], v[1], v[2], v[3]);
            *(float4*)&outF[(size_t)n * 64 + c * 8 + 4] = make_float4(v[4], v[5], v[6], v[7]);
        }
    }
}

// ---------------- epilogue ----------------

__global__ void k_pool1(const float* __restrict__ h, float* __restrict__ partial) {
    int blk = blockIdx.x;
    int g = blk / POOL_CHUNKS, c = blk % POOL_CHUNKS;
    int wave = threadIdx.x >> 6, lane = threadIdx.x & 63;
    int base = g * NODES_PER_GRAPH + c * POOL_NODES_PER_CHUNK;
    float acc = 0.f;
    for (int i = wave; i < POOL_NODES_PER_CHUNK; i += 4)
        acc += h[(size_t)(base + i) * 64 + lane];
    __shared__ float buf[4][64];
    buf[wave][lane] = acc;
    __syncthreads();
    if (wave == 0)
        partial[blk * 64 + lane] = buf[0][lane] + buf[1][lane] + buf[2][lane] + buf[3][lane];
}

// fused pool-stage-2 + value head: 10 blocks x 512 threads.
__global__ void k_pool2_value(const float* __restrict__ partial,
                              const float* __restrict__ Wv1, const float* __restrict__ bv1,
                              const float* __restrict__ Wv2, const float* __restrict__ bv2,
                              float* __restrict__ pooled, float* __restrict__ value) {
    int g = blockIdx.x;
    int j = threadIdx.x;   // 512
    __shared__ float pl[64];
    if (j < 64) {
        float a = 0.f;
        for (int cc = 0; cc < POOL_CHUNKS; ++cc)
            a += partial[(g * POOL_CHUNKS + cc) * 64 + j];
        a *= (1.0f / NODES_PER_GRAPH);
        pooled[g * 64 + j] = a;
        pl[j] = a;
    }
    __syncthreads();
    float acc = bv1[j];
    for (int cc = 0; cc < 64; ++cc) acc += pl[cc] * Wv1[cc * 512 + j];
    acc = fmaxf(acc, 0.f);
    float t = acc * Wv2[j];
    for (int w = 32; w >= 1; w >>= 1) t += __shfl_xor(t, w);
    __shared__ float red[8];
    int wave = j >> 6, lane = j & 63;
    if (lane == 0) red[wave] = t;
    __syncthreads();
    if (j == 0) {
        float v = 0.f;
        for (int w = 0; w < 8; ++w) v += red[w];
        value[g] = v + bv2[0];
    }
}

// ---------------- launcher ----------------

extern "C" void kernel_launch(void* const* d_in, const int* in_sizes, int n_in,
                              void* d_out, int out_size, void* d_ws, size_t ws_size,
                              hipStream_t stream) {
    const float* x   = (const float*)d_in[0];
    const int*   ei  = (const int*)d_in[1];     // (2, E): row0=src, row1=dst
    const float* W1  = (const float*)d_in[2];
    const float* as1 = (const float*)d_in[3];
    const float* ad1 = (const float*)d_in[4];
    const float* b1  = (const float*)d_in[5];
    const float* Wh  = (const float*)d_in[6];   // (2,64,64)
    const float* ash = (const float*)d_in[7];
    const float* adh = (const float*)d_in[8];
    const float* bh  = (const float*)d_in[9];
    const float* W2  = (const float*)d_in[10];
    const float* as2 = (const float*)d_in[11];
    const float* ad2 = (const float*)d_in[12];
    const float* b2  = (const float*)d_in[13];
    const float* Wv1 = (const float*)d_in[14];
    const float* bv1 = (const float*)d_in[15];
    const float* Wv2 = (const float*)d_in[16];
    const float* bv2 = (const float*)d_in[17];

    const int* e_src = ei;
    const int* e_dst = ei + EE;

    // workspace carve-up (256B aligned)
    char* p = (char*)d_ws;
    auto carve = [&](size_t bytes) {
        char* r = p;
        p += (bytes + 255) & ~(size_t)255;
        return r;
    };
    int*    counts    = (int*)carve(NN * 4);
    int*    offsets   = (int*)carve((NN + 1) * 4);
    int*    cursors   = (int*)carve(NN * 4);
    int*    ssrc      = (int*)carve(TOT_EDGES * 4);
    int*    blocksums = (int*)carve(SCAN_GRID * 4);
    __half* wpack     = (__half*)carve(3 * 8 * 64 * 8 * 2);    // packed W fragments
    __half* bufH      = (__half*)carve((size_t)NN * 64 * 2);   // fp16 gather table
    __half* bufB16    = (__half*)carve((size_t)NN * 64 * 2);   // fp16 layer boundary
    float*  es        = (float*)carve(NN * 4);
    float*  ed        = (float*)carve(NN * 4);
    float*  partial   = (float*)carve((size_t)NUM_GRAPHS * POOL_CHUNKS * 64 * 4);

    float* out_h      = (float*)d_out;                 // [N, 64]
    float* out_pooled = out_h + (size_t)NN * 64;       // [10, 64]
    float* out_value  = out_pooled + NUM_GRAPHS * 64;  // [10]

    // CSR build (reused by all 4 layers) + W packing
    hipMemsetAsync(counts, 0, NN * 4, stream);
    k_count_part<<<NPART * CSR_CHUNKS, 256, 0, stream>>>(e_dst, counts);
    k_scan1<<<SCAN_GRID, SCAN_BLK, 0, stream>>>(counts, offsets, blocksums);
    k_scan2<<<1, 64, 0, stream>>>(blocksums, offsets);
    k_scan3<<<SCAN_GRID, SCAN_BLK, 0, stream>>>(offsets, cursors, blocksums);
    k_scatter_part<<<NPART * CSR_CHUNKS, 256, 0, stream>>>(e_src, e_dst, cursors, ssrc);
    k_wpack<<<6, 256, 0, stream>>>(Wh, W2, wpack);

    const int HBLK = (NN + 3) / 4;             // aggregate: 4 waves/block, 1 node/wave
    const int HC_WAVES = HC_BLOCKS * 256 / 64; // 4096
    const int WPL = 8 * 64 * 8;                // wpack halves per layer

    // layer 1: FD -> C (scalar), relu; boundary buffer is fp16
    k_hcompute_f3<<<HC_BLOCKS, 256, 0, stream>>>(x, W1, as1, ad1, bufH, es, ed, HC_WAVES);
    k_aggregate<1><<<HBLK, 256, 0, stream>>>(bufH, es, ed, offsets, ssrc, b1, bufB16, nullptr);

    // hidden layers: C -> C via MFMA, relu in aggregate
    for (int i = 0; i < 2; ++i) {
        k_hc_mfma<<<MFMA_BLOCKS, 256, 0, stream>>>(bufB16, wpack + i * WPL,
                                                   ash + i * 64, adh + i * 64,
                                                   bufH, es, ed);
        k_aggregate<1><<<HBLK, 256, 0, stream>>>(bufH, es, ed, offsets, ssrc, bh + i * 64,
                                                 bufB16, nullptr);
    }

    // layer 4: C -> OUT via MFMA, no relu, write straight to d_out (fp32)
    k_hc_mfma<<<MFMA_BLOCKS, 256, 0, stream>>>(bufB16, wpack + 2 * WPL, as2, ad2,
                                               bufH, es, ed);
    k_aggregate<0><<<HBLK, 256, 0, stream>>>(bufH, es, ed, offsets, ssrc, b2, nullptr, out_h);

    // pooling + value head
    k_pool1<<<NUM_GRAPHS * POOL_CHUNKS, 256, 0, stream>>>(out_h, partial);
    k_pool2_value<<<NUM_GRAPHS, 512, 0, stream>>>(partial, Wv1, bv1, Wv2, bv2,
                                                  out_pooled, out_value);
}